// Round 13
// baseline (100.209 us; speedup 1.0000x reference)
//
#include <hip/hip_runtime.h>
#include <stdint.h>

// Problem constants
#define S_LEN 2048
#define D_DIM 1024
#define NB 2
#define NH 16
#define NE 64
#define N_COLS (3 * NH * NE)  // 3072 (Q | K | V column blocks)
#define K_DIM D_DIM           // 1024

typedef unsigned short u16;
typedef unsigned int u32;
typedef u16 u16x8 __attribute__((ext_vector_type(8)));
typedef __bf16 bf16x8 __attribute__((ext_vector_type(8)));
typedef __bf16 bf16x4 __attribute__((ext_vector_type(4)));
typedef float f32x4 __attribute__((ext_vector_type(4)));

__device__ __forceinline__ u16 f2b(float f) {
  u32 u = __builtin_bit_cast(u32, f);
  return (u16)((u + 0x7FFFu + ((u >> 16) & 1u)) >> 16);  // RNE
}

__device__ __forceinline__ void gload_lds16(const void* g, void* l) {
  __builtin_amdgcn_global_load_lds(
      (const __attribute__((address_space(1))) u32*)g,
      (__attribute__((address_space(3))) u32*)l, 16, 0, 0);
}

// ---------- merged prep: blocks [0,2048) convert x; [2048,2816) transpose W ----------
__global__ __launch_bounds__(256) void k_prep(const float* __restrict__ x,
                                              const float* __restrict__ Wq,
                                              const float* __restrict__ Wk,
                                              const float* __restrict__ Wv,
                                              u16* __restrict__ xb,
                                              u16* __restrict__ Wt) {
  __shared__ u16 tile[64][65];
  int bid = blockIdx.x;
  int t = threadIdx.x;
  if (bid < 2048) {
    size_t i = (size_t)bid * 256 + t;
    const float4* xf = (const float4*)x;
    float4 a = xf[2 * i], c = xf[2 * i + 1];
    u16x8 o;
    o[0] = f2b(a.x); o[1] = f2b(a.y); o[2] = f2b(a.z); o[3] = f2b(a.w);
    o[4] = f2b(c.x); o[5] = f2b(c.y); o[6] = f2b(c.z); o[7] = f2b(c.w);
    *(u16x8*)(xb + 8 * i) = o;
  } else {
    int wbid = bid - 2048;             // proj*256 + h*16 + kb
    int kb = wbid & 15;
    int h = (wbid >> 4) & 15;
    int proj = wbid >> 8;
    const float* W = (proj == 0) ? Wq : ((proj == 1) ? Wk : Wv);
    int k0 = kb * 64;
    int e = t & 63, kr = t >> 6;
    const float* src = W + ((size_t)h * D_DIM + k0 + kr * 16) * NE + e;
#pragma unroll
    for (int j = 0; j < 16; ++j) tile[kr * 16 + j][e] = f2b(src[(size_t)j * NE]);
    __syncthreads();
    int e2 = t >> 2, kc = (t & 3) * 16;
    u16x8 o0, o1;
#pragma unroll
    for (int j = 0; j < 8; ++j) { o0[j] = tile[kc + j][e2]; o1[j] = tile[kc + 8 + j][e2]; }
    size_t n = (size_t)proj * 1024 + h * 64 + e2;
    u16* dst = Wt + n * K_DIM + k0 + kc;
    *(u16x8*)dst = o0;
    *(u16x8*)(dst + 8) = o1;
  }
}

// ------------- GEMM: qkv[4096,3072] = xb[4096,1024] @ Wt[3072,1024]^T -------------
__global__ __launch_bounds__(256) void k_gemm(const u16* __restrict__ A,
                                              const u16* __restrict__ Bt,
                                              u16* __restrict__ C) {
  __shared__ __align__(16) u16 As[128 * 64];
  __shared__ __align__(16) u16 Bs[128 * 64];
  int t = threadIdx.x;
  int lane = t & 63, w = t >> 6;
  int wr = (w >> 1) * 64, wc = (w & 1) * 64;
  int bid = blockIdx.x;
  int xcd = bid & 7, r0 = bid >> 3;          // r0 in [0,96)
  int m0 = (r0 / 3) * 128;
  int n0 = (xcd * 3 + (r0 % 3)) * 128;
  float qscale = ((n0 + wc) < 1024) ? 0.18033688f : 1.0f;  // 0.125*log2e
  f32x4 acc[4][4];
#pragma unroll
  for (int m = 0; m < 4; m++)
#pragma unroll
    for (int n = 0; n < 4; n++)
#pragma unroll
      for (int j = 0; j < 4; j++) acc[m][n][j] = 0.f;

  for (int k0 = 0; k0 < K_DIM; k0 += 64) {
#pragma unroll
    for (int i = 0; i < 4; ++i) {
      int ci = i * 256 + t;
      int row = ci >> 3, c = ci & 7;
      int cs = c ^ (row & 7);
      gload_lds16(A + (size_t)(m0 + row) * K_DIM + k0 + cs * 8,
                  (char*)As + (size_t)(i * 256 + w * 64) * 16);
      gload_lds16(Bt + (size_t)(n0 + row) * K_DIM + k0 + cs * 8,
                  (char*)Bs + (size_t)(i * 256 + w * 64) * 16);
    }
    __syncthreads();
#pragma unroll
    for (int ks = 0; ks < 2; ++ks) {
      int kc = ks * 4 + (lane >> 4);
      bf16x8 af[4], bfr[4];
#pragma unroll
      for (int m = 0; m < 4; m++) {
        int r = wr + m * 16 + (lane & 15);
        af[m] = *(const bf16x8*)&As[r * 64 + ((kc ^ (r & 7)) * 8)];
      }
#pragma unroll
      for (int n = 0; n < 4; n++) {
        int r = wc + n * 16 + (lane & 15);
        bfr[n] = *(const bf16x8*)&Bs[r * 64 + ((kc ^ (r & 7)) * 8)];
      }
#pragma unroll
      for (int m = 0; m < 4; m++)
#pragma unroll
        for (int n = 0; n < 4; n++)
          acc[m][n] = __builtin_amdgcn_mfma_f32_16x16x32_bf16(af[m], bfr[n], acc[m][n], 0, 0, 0);
    }
    __syncthreads();
  }
#pragma unroll
  for (int m = 0; m < 4; m++) {
#pragma unroll
    for (int r = 0; r < 4; r++) {
      int row = m0 + wr + m * 16 + (lane >> 4) * 4 + r;
#pragma unroll
      for (int n = 0; n < 4; n++) {
        int col = n0 + wc + n * 16 + (lane & 15);
        C[(size_t)row * N_COLS + col] = f2b(acc[m][n][r] * qscale);
      }
    }
  }
}

// ---- attention helpers (256-thread block) ----
__device__ __forceinline__ void stage_k(const u16* kb_, u16* kdst, int kv0, int t, int w) {
#pragma unroll
  for (int i = 0; i < 2; ++i) {
    int ci = i * 256 + t;
    int row = ci >> 3, c = ci & 7;
    int cs = c ^ (row & 7);
    gload_lds16(kb_ + (size_t)(kv0 + row) * N_COLS + cs * 8,
                (char*)kdst + (size_t)(i * 256 + w * 64) * 16);  // wave-uniform base
  }
}

// V write: thread covers kv pair vp = t>>3, e-chunk vec = t&7.
// Vt element (e,kv) at byte e*128 + slot*16 + (kv&7)*2, slot=(kv>>3)^(e&7)^(e>>3).
__device__ __forceinline__ void vwrite(u16* vt, u16x8 va, u16x8 vb2, int vp, int vec) {
#pragma unroll
  for (int j = 0; j < 8; ++j) {
    int e = vec * 8 + j;
    int slot = (vp >> 2) ^ (e & 7) ^ (e >> 3);
    *(u32*)((char*)vt + e * 128 + slot * 16 + (vp & 3) * 4) =
        (u32)va[j] | ((u32)vb2[j] << 16);
  }
}

// ------- flash attention, causal, swapped-QK^T register-P, kv-split balance -------
// No-max softmax => partial (O,l) over disjoint kv ranges combine by ADDITION
// (order-independent for 2 addends -> deterministic). q-tiles qt>=16 split into
// 2 kv-chunks handled by separate blocks: chunk0 -> raw (O0,l0) to ws; chunk1 ->
// raw O to out + l1 to ws; k_fix combines. qt<16 store normalized directly.
// Grid 1536 = 8 xcd x 192: x=bid&7, r=bid>>3; bh=x*4+(r&3) (4 heads/XCD L2);
// u=r>>2 in [0,48): u<32 -> qt=31-(u>>1), chunk c=u&1; u>=32 -> qt=47-u whole.
// Max 16 steps/block (vs 32 unsplit) -> ~2x better CU-time balance.
__global__ __launch_bounds__(256) void k_attn(const u16* __restrict__ qkv,
                                              float* __restrict__ out,
                                              float* __restrict__ O0,
                                              float* __restrict__ l0,
                                              float* __restrict__ l1) {
  __shared__ __align__(16) u16 Ks[2][64 * 64];
  __shared__ __align__(16) u16 Vt[2][64 * 64];
  int t = threadIdx.x;
  int lane = t & 63, w = t >> 6;
  int hi = lane >> 4, l15 = lane & 15;
  int bid = blockIdx.x;                 // 0..1535
  int x = bid & 7, r_ = bid >> 3;
  int bh = x * 4 + (r_ & 3);
  int u = r_ >> 2;
  int qt, c;
  if (u < 32) { qt = 31 - (u >> 1); c = u & 1; }
  else        { qt = 47 - u;        c = 0;     }
  int nt = qt + 1;
  int halfn = (nt + 1) >> 1;
  bool split = (u < 32);
  int lo = (split && c) ? halfn : 0;
  int te = split ? (c ? nt : halfn) : nt;   // tile range [lo, te)
  int b = bh >> 4, h = bh & 15;
  const u16* qb_ = qkv + (size_t)b * S_LEN * N_COLS + h * NE;
  const u16* kb_ = qb_ + 1024;
  const u16* vb_ = qb_ + 2048;
  int vp = t >> 3, vec = t & 7;

  int q0 = qt * 64;
  int wqb = q0 + w * 16;                // wave q base; lane q = wqb + l15

  bf16x8 qf[2];
#pragma unroll
  for (int ks = 0; ks < 2; ks++)
    qf[ks] = *(const bf16x8*)(qb_ + (size_t)(wqb + l15) * N_COLS + ks * 32 + hi * 8);

  f32x4 o[4];
#pragma unroll
  for (int i = 0; i < 4; i++)
#pragma unroll
    for (int j = 0; j < 4; j++) o[i][j] = 0.f;
  float lsum = 0.f;
  int myq = wqb + l15;

  // prologue: stage tile lo into buffer 0
  stage_k(kb_, Ks[0], lo * 64, t, w);
  {
    const u16* vs = vb_ + (size_t)(lo * 64 + 2 * vp) * N_COLS + vec * 8;
    u16x8 va = *(const u16x8*)vs;
    u16x8 vb2 = *(const u16x8*)(vs + N_COLS);
    vwrite(Vt[0], va, vb2, vp, vec);
  }
  __syncthreads();

  int cur = 0;
  for (int ti = lo; ti < te; ++ti) {
    int kv0 = ti * 64;
    bool pf = (ti + 1 < te);
    u16x8 va, vb2;
    if (pf) {
      const u16* vs = vb_ + (size_t)(kv0 + 64 + 2 * vp) * N_COLS + vec * 8;
      va = *(const u16x8*)vs;            // in flight during QK^T+softmax
      vb2 = *(const u16x8*)(vs + N_COLS);
      stage_k(kb_, Ks[cur ^ 1], kv0 + 64, t, w);
    }

    // S^T = K Q : s[f][r] = S[kv = kv0+16f+4hi+r][q = myq]
    f32x4 s[4];
#pragma unroll
    for (int f = 0; f < 4; f++)
#pragma unroll
      for (int j = 0; j < 4; j++) s[f][j] = 0.f;
    __builtin_amdgcn_s_setprio(1);
#pragma unroll
    for (int ks = 0; ks < 2; ks++) {
      int kc = ks * 4 + hi;
#pragma unroll
      for (int f = 0; f < 4; f++) {
        int r = f * 16 + l15;
        bf16x8 kf = *(const bf16x8*)&Ks[cur][r * 64 + ((kc ^ (r & 7)) * 8)];
        s[f] = __builtin_amdgcn_mfma_f32_16x16x32_bf16(kf, qf[ks], s[f], 0, 0, 0);
      }
    }
    __builtin_amdgcn_s_setprio(0);

    // no-max softmax: p = exp2(s); mask diagonal tile (only reachable if te==nt)
    bool diag = (ti == nt - 1);
#pragma unroll
    for (int f = 0; f < 4; f++) {
#pragma unroll
      for (int r = 0; r < 4; r++) {
        float p = __builtin_amdgcn_exp2f(s[f][r]);
        if (diag) {
          int kv = kv0 + f * 16 + 4 * hi + r;
          p = (kv <= myq) ? p : 0.f;
        }
        s[f][r] = p;
        lsum += p;
      }
    }

    // T14 write-late: V prefetch regs -> next buffer
    if (pf) vwrite(Vt[cur ^ 1], va, vb2, vp, vec);

    // PV: pa register-local; V read with the matching k-permutation (2 x b64)
    __builtin_amdgcn_s_setprio(1);
#pragma unroll
    for (int ks = 0; ks < 2; ks++) {
      bf16x8 pa;
#pragma unroll
      for (int j = 0; j < 4; j++) {
        pa[j] = (__bf16)s[2 * ks][j];
        pa[4 + j] = (__bf16)s[2 * ks + 1][j];
      }
      int kvo1 = 32 * ks + 4 * hi;       // j<4  -> kv = kvo1 + j
      int kvo2 = kvo1 + 16;              // j>=4 -> kv = kvo2 + (j-4)
#pragma unroll
      for (int ef = 0; ef < 4; ef++) {
        int e = ef * 16 + l15;
        int sw = (e & 7) ^ (e >> 3);
        int a1 = e * 128 + (((kvo1 >> 3) ^ sw) * 16) + (kvo1 & 7) * 2;
        int a2 = e * 128 + (((kvo2 >> 3) ^ sw) * 16) + (kvo2 & 7) * 2;
        bf16x4 vlo = *(const bf16x4*)((const char*)Vt[cur] + a1);
        bf16x4 vhi = *(const bf16x4*)((const char*)Vt[cur] + a2);
        bf16x8 vbf;
#pragma unroll
        for (int j = 0; j < 4; j++) { vbf[j] = vlo[j]; vbf[4 + j] = vhi[j]; }
        o[ef] = __builtin_amdgcn_mfma_f32_16x16x32_bf16(pa, vbf, o[ef], 0, 0, 0);
      }
    }
    __builtin_amdgcn_s_setprio(0);
    __syncthreads();
    cur ^= 1;
  }

  // complete row-sum across hi groups (all lanes get total for q = wqb + l15)
  lsum += __shfl_xor(lsum, 16);
  lsum += __shfl_xor(lsum, 32);

  if (!split) {
    // normalized direct store
#pragma unroll
    for (int r = 0; r < 4; r++) {
      float l = __shfl(lsum, 4 * hi + r);
      float inv = 1.0f / l;
      int q = wqb + 4 * hi + r;
#pragma unroll
      for (int ef = 0; ef < 4; ef++) {
        int col = h * NE + ef * 16 + l15;
        out[((size_t)b * S_LEN + q) * (NH * NE) + col] = o[ef][r] * inv;
      }
    }
  } else {
    int sp = bh * 16 + (qt - 16);        // split-tile id 0..511
    if (c == 0) {
      // raw partial to ws
#pragma unroll
      for (int r = 0; r < 4; r++) {
        int row = w * 16 + 4 * hi + r;
#pragma unroll
        for (int ef = 0; ef < 4; ef++)
          O0[(size_t)sp * 4096 + row * 64 + ef * 16 + l15] = o[ef][r];
      }
      if (lane < 16) l0[sp * 64 + w * 16 + l15] = lsum;
    } else {
      // raw partial straight to out (combined+normalized by k_fix)
#pragma unroll
      for (int r = 0; r < 4; r++) {
        int q = wqb + 4 * hi + r;
#pragma unroll
        for (int ef = 0; ef < 4; ef++) {
          int col = h * NE + ef * 16 + l15;
          out[((size_t)b * S_LEN + q) * (NH * NE) + col] = o[ef][r];
        }
      }
      if (lane < 16) l1[sp * 64 + w * 16 + l15] = lsum;
    }
  }
}

// ---- combine split partials: out = (out + O0) / (l0 + l1), split rows only ----
__global__ __launch_bounds__(256) void k_fix(float* __restrict__ out,
                                             const float* __restrict__ O0,
                                             const float* __restrict__ l0,
                                             const float* __restrict__ l1) {
  int f = (blockIdx.x * 256 + threadIdx.x) * 4;   // over 512*64*64 = 2M elems
  int sp = f >> 12;
  int row = (f >> 6) & 63;
  int e0 = f & 63;
  int bh = sp >> 4, qt = 16 + (sp & 15);
  int b = bh >> 4, h = bh & 15;
  int q = qt * 64 + row;
  float inv = 1.0f / (l0[sp * 64 + row] + l1[sp * 64 + row]);
  float4 p0 = *(const float4*)&O0[(size_t)sp * 4096 + row * 64 + e0];
  size_t oi = ((size_t)b * S_LEN + q) * (NH * NE) + h * NE + e0;
  float4 cu = *(float4*)&out[oi];
  float4 res;
  res.x = (cu.x + p0.x) * inv;
  res.y = (cu.y + p0.y) * inv;
  res.z = (cu.z + p0.z) * inv;
  res.w = (cu.w + p0.w) * inv;
  *(float4*)&out[oi] = res;
}

extern "C" void kernel_launch(void* const* d_in, const int* in_sizes, int n_in,
                              void* d_out, int out_size, void* d_ws, size_t ws_size,
                              hipStream_t stream) {
  const float* x = (const float*)d_in[0];
  const float* Wq = (const float*)d_in[1];
  const float* Wk = (const float*)d_in[2];
  const float* Wv = (const float*)d_in[3];
  float* out = (float*)d_out;

  char* ws = (char*)d_ws;
  u16* xb = (u16*)ws;                          // 4096*1024*2  = 8 MB
  u16* Wt = (u16*)(ws + (8u << 20));           // 3072*1024*2  = 6 MB
  u16* qkv = (u16*)(ws + (14u << 20));         // 4096*3072*2  = 24 MB
  // attn partials alias the xb/Wt region (dead after k_gemm):
  float* O0 = (float*)ws;                      // 512*4096*4   = 8 MB
  float* l0 = (float*)(ws + (8u << 20));       // 128 KB
  float* l1 = (float*)(ws + (8u << 20) + (128u << 10));  // 128 KB

  k_prep<<<dim3(2816), dim3(256), 0, stream>>>(x, Wq, Wk, Wv, xb, Wt);
  k_gemm<<<dim3(768), dim3(256), 0, stream>>>(xb, Wt, qkv);
  k_attn<<<dim3(1536), dim3(256), 0, stream>>>(qkv, out, O0, l0, l1);
  k_fix<<<dim3(2048), dim3(256), 0, stream>>>(out, O0, l0, l1);
}